// Round 1
// baseline (463.830 us; speedup 1.0000x reference)
//
#include <hip/hip_runtime.h>
#include <hip/hip_bf16.h>

typedef __attribute__((ext_vector_type(4))) float f32x4;
typedef __attribute__((ext_vector_type(8))) short bf16x8;

#define IN_DIM 4096
#define OUT_DIM 4096
#define MROWS 8192   // B*S = 4*2048
#define NFREQ 8
#define BM 128
#define BN 128
#define BK 32
#define NKT (IN_DIM / BK)
#define TWO_PI 6.283185307179586f

// f32 -> bf16 bits, round-to-nearest-even
__device__ __forceinline__ unsigned int f2bf(float f) {
    union { float f; unsigned int u; } a;
    a.f = f;
    unsigned int u = a.u;
    u += 0x7fffu + ((u >> 16) & 1u);
    return u >> 16;
}

// ---------------------------------------------------------------------------
// Kernel 1: W_dora (bf16) = m * (W + irfft2(pad(delta))) / (rownorm + eps)
// irfft2 of an 8x8 low-frequency corner collapses (by linearity of the FFT) to
//   dW[o,i] = (1/4096) * sum_{h,w} c_w * ( A_hw cos(a) - B_hw sin(a) ),
//   a = 2*pi*(h*o + w*i)/4096,  A=2*dr, B=2*di,  c_w = (w==0 ? 1 : 2).
// (w=0 keeps only Re of the DC bin -> same formula, imag part never enters.)
// One block per output row o; 256 threads * 16 elements each.
// ---------------------------------------------------------------------------
__global__ __launch_bounds__(256) void dora_weight_kernel(
    const float* __restrict__ W,
    const float* __restrict__ dre,
    const float* __restrict__ dimg,
    const float* __restrict__ mrow,
    unsigned short* __restrict__ Wd)
{
    const int o = blockIdx.x;
    const int t = threadIdx.x;

    // Per-row spectral sums over h:  P[w] = Re(H[o,w]), Q[w] = Im(H[o,w])
    float P[NFREQ], Q[NFREQ];
#pragma unroll
    for (int w = 0; w < NFREQ; ++w) { P[w] = 0.f; Q[w] = 0.f; }
#pragma unroll
    for (int h = 0; h < NFREQ; ++h) {
        const float th = (TWO_PI / 4096.0f) * (float)((h * o) & 4095);
        float sh, ch;
        sincosf(th, &sh, &ch);
#pragma unroll
        for (int w = 0; w < NFREQ; ++w) {
            const float A = 2.0f * dre[h * NFREQ + w];
            const float B = 2.0f * dimg[h * NFREQ + w];
            P[w] += A * ch - B * sh;
            Q[w] += A * sh + B * ch;
        }
    }
#pragma unroll
    for (int w = 0; w < NFREQ; ++w) {
        const float c = (w == 0 ? 1.0f : 2.0f) * (1.0f / 4096.0f);
        P[w] *= c; Q[w] *= c;
    }

    const int i0 = t * 16;
    const f32x4* wrow = (const f32x4*)(W + (size_t)o * IN_DIM + i0);
    float vals[16];
    float ss = 0.0f;
#pragma unroll
    for (int q = 0; q < 4; ++q) {
        const f32x4 wv = wrow[q];
#pragma unroll
        for (int j = 0; j < 4; ++j) {
            const int i = i0 + q * 4 + j;
            const float beta = (TWO_PI / 4096.0f) * (float)i;
            float sb, cb;
            sincosf(beta, &sb, &cb);
            // Chebyshev-style recurrence over w multiples of beta
            float cw = cb, sw = sb;
            float d = P[0] + P[1] * cw - Q[1] * sw;
#pragma unroll
            for (int w = 2; w < NFREQ; ++w) {
                const float cn = cw * cb - sw * sb;
                sw = sw * cb + cw * sb;
                cw = cn;
                d += P[w] * cw - Q[w] * sw;
            }
            const float v = wv[j] + d;
            vals[q * 4 + j] = v;
            ss += v * v;
        }
    }

    // block reduction of sum-of-squares (wave shuffle + LDS across 4 waves)
#pragma unroll
    for (int off = 32; off > 0; off >>= 1)
        ss += __shfl_down(ss, off, 64);
    __shared__ float red[4];
    if ((t & 63) == 0) red[t >> 6] = ss;
    __syncthreads();
    const float n2 = red[0] + red[1] + red[2] + red[3];
    const float scale = mrow[o] / (sqrtf(n2) + 1e-8f);

    unsigned int wds[8];
#pragma unroll
    for (int k = 0; k < 8; ++k)
        wds[k] = f2bf(vals[2 * k] * scale) | (f2bf(vals[2 * k + 1] * scale) << 16);
    uint4* dst = (uint4*)(Wd + (size_t)o * IN_DIM + i0);
    dst[0] = make_uint4(wds[0], wds[1], wds[2], wds[3]);
    dst[1] = make_uint4(wds[4], wds[5], wds[6], wds[7]);
}

// ---------------------------------------------------------------------------
// Kernel 2: x (f32) -> bf16, 8 elements/thread, vectorized
// ---------------------------------------------------------------------------
__global__ __launch_bounds__(256) void cvt_kernel(
    const float* __restrict__ x, unsigned short* __restrict__ xb)
{
    const size_t idx = (size_t)blockIdx.x * 256 + threadIdx.x; // one per 8 elems
    const f32x4* p = (const f32x4*)(x + idx * 8);
    const f32x4 a = p[0], b = p[1];
    uint4 o;
    o.x = f2bf(a[0]) | (f2bf(a[1]) << 16);
    o.y = f2bf(a[2]) | (f2bf(a[3]) << 16);
    o.z = f2bf(b[0]) | (f2bf(b[1]) << 16);
    o.w = f2bf(b[2]) | (f2bf(b[3]) << 16);
    *(uint4*)(xb + idx * 8) = o;
}

// ---------------------------------------------------------------------------
// Kernel 3: out[M,N] = Xbf16[M,K] @ Wd[N,K]^T + bias   (bf16 MFMA, f32 acc)
// m97 structure: 128x128 tile, BK=32, 4 waves (2x2 of 64x64), double-buffered
// LDS, global_load_lds width=16 staging. XB=false falls back to reg-staging
// the f32 x with inline conversion (used only if ws is too small for x-bf16).
// ---------------------------------------------------------------------------
template <bool XB>
__global__ __launch_bounds__(256) void gemm_kernel(
    const float* __restrict__ Xf,
    const unsigned short* __restrict__ Xb,
    const unsigned short* __restrict__ Wd,
    const float* __restrict__ bias,
    float* __restrict__ out)
{
    __shared__ unsigned short As[2][BM * BK];
    __shared__ unsigned short Bs[2][BN * BK];

    const int t = threadIdx.x;
    const int wid = t >> 6, lane = t & 63;
    const int wr = wid >> 1, wc = wid & 1;
    const int m0 = blockIdx.x * BM, n0 = blockIdx.y * BN;
    const int fr = lane & 15, fq = lane >> 4;

    f32x4 acc[4][4] = {};

    // global_load_lds staging: linear LDS, wave-uniform base + lane*16B.
    // linear elem idx = r*2048 + wid*512 + lane*8  ->  row = idx/32, col = idx%32
    const int srow = wid * 16 + (lane >> 2);
    const int scol = (lane & 3) * 8;
    const unsigned short* bsrc0 = Wd + (size_t)(n0 + srow) * IN_DIM + scol;
    const unsigned short* bsrc1 = bsrc0 + (size_t)64 * IN_DIM;
    const unsigned short* asrc0 = Xb + (size_t)(m0 + srow) * IN_DIM + scol;
    const unsigned short* asrc1 = asrc0 + (size_t)64 * IN_DIM;
    const int lds_off = wid * 512; // elements, uniform per wave

    auto stage16 = [&](unsigned short* ldsbase, const unsigned short* g0,
                       const unsigned short* g1, int kt) {
        const unsigned short* p0 = g0 + kt * BK;
        const unsigned short* p1 = g1 + kt * BK;
        __builtin_amdgcn_global_load_lds(
            (const __attribute__((address_space(1))) void*)p0,
            (__attribute__((address_space(3))) void*)(ldsbase + lds_off), 16, 0, 0);
        __builtin_amdgcn_global_load_lds(
            (const __attribute__((address_space(1))) void*)p1,
            (__attribute__((address_space(3))) void*)(ldsbase + 2048 + lds_off), 16, 0, 0);
    };

    // reg-staging coords (fallback path): thread t -> row t/2, k-half (t&1)*16
    const int ar = t >> 1;
    const int ak = (t & 1) * 16;
    const float* afp = Xf + (size_t)(m0 + ar) * IN_DIM + ak;
    const int a_lds_off = ar * BK + ak;

    auto writeA = [&](int buf, const f32x4* v) {
        unsigned int w[8];
#pragma unroll
        for (int k = 0; k < 4; ++k) {
            w[2 * k]     = f2bf(v[k][0]) | (f2bf(v[k][1]) << 16);
            w[2 * k + 1] = f2bf(v[k][2]) | (f2bf(v[k][3]) << 16);
        }
        uint4* d = (uint4*)(&As[buf][a_lds_off]);
        d[0] = make_uint4(w[0], w[1], w[2], w[3]);
        d[1] = make_uint4(w[4], w[5], w[6], w[7]);
    };

    // prologue: stage tile 0
    if constexpr (XB) {
        stage16(As[0], asrc0, asrc1, 0);
    }
    stage16(Bs[0], bsrc0, bsrc1, 0);
    if constexpr (!XB) {
        f32x4 av[4];
        const f32x4* ap = (const f32x4*)afp;
        av[0] = ap[0]; av[1] = ap[1]; av[2] = ap[2]; av[3] = ap[3];
        writeA(0, av);
    }
    __syncthreads();

    for (int kt = 0; kt < NKT; ++kt) {
        const int cur = kt & 1;
        const bool more = (kt + 1 < NKT);
        f32x4 nv[4];
        if (more) {
            if constexpr (XB) {
                stage16(As[cur ^ 1], asrc0, asrc1, kt + 1);
            } else {
                const f32x4* ap = (const f32x4*)(afp + (size_t)(kt + 1) * BK);
                nv[0] = ap[0]; nv[1] = ap[1]; nv[2] = ap[2]; nv[3] = ap[3];
            }
            stage16(Bs[cur ^ 1], bsrc0, bsrc1, kt + 1);
        }

        bf16x8 afrag[4], bfrag[4];
#pragma unroll
        for (int mf = 0; mf < 4; ++mf)
            afrag[mf] = *(const bf16x8*)(&As[cur][(wr * 64 + mf * 16 + fr) * BK + fq * 8]);
#pragma unroll
        for (int nf = 0; nf < 4; ++nf)
            bfrag[nf] = *(const bf16x8*)(&Bs[cur][(wc * 64 + nf * 16 + fr) * BK + fq * 8]);
#pragma unroll
        for (int mf = 0; mf < 4; ++mf)
#pragma unroll
            for (int nf = 0; nf < 4; ++nf)
                acc[mf][nf] = __builtin_amdgcn_mfma_f32_16x16x32_bf16(
                    afrag[mf], bfrag[nf], acc[mf][nf], 0, 0, 0);

        if constexpr (!XB) {
            if (more) writeA(cur ^ 1, nv);
        }
        __syncthreads();
    }

    // epilogue: C/D layout col = lane&15, row = (lane>>4)*4 + reg
#pragma unroll
    for (int nf = 0; nf < 4; ++nf) {
        const int col = n0 + wc * 64 + nf * 16 + fr;
        const float bv = bias[col];
#pragma unroll
        for (int mf = 0; mf < 4; ++mf) {
            const int row = m0 + wr * 64 + mf * 16 + fq * 4;
            float* op = out + (size_t)row * OUT_DIM + col;
            op[0 * OUT_DIM] = acc[mf][nf][0] + bv;
            op[1 * OUT_DIM] = acc[mf][nf][1] + bv;
            op[2 * OUT_DIM] = acc[mf][nf][2] + bv;
            op[3 * OUT_DIM] = acc[mf][nf][3] + bv;
        }
    }
}

extern "C" void kernel_launch(void* const* d_in, const int* in_sizes, int n_in,
                              void* d_out, int out_size, void* d_ws, size_t ws_size,
                              hipStream_t stream) {
    const float* x    = (const float*)d_in[0];
    const float* W    = (const float*)d_in[1];
    const float* bias = (const float*)d_in[2];
    const float* dre  = (const float*)d_in[3];
    const float* dimg = (const float*)d_in[4];
    const float* mrow = (const float*)d_in[5];
    float* out = (float*)d_out;

    unsigned short* Wd = (unsigned short*)d_ws;
    const size_t WD_BYTES = (size_t)OUT_DIM * IN_DIM * 2;   // 32 MiB
    const size_t XB_BYTES = (size_t)MROWS * IN_DIM * 2;     // 64 MiB
    unsigned short* Xb = (unsigned short*)((char*)d_ws + WD_BYTES);
    const bool fast = ws_size >= WD_BYTES + XB_BYTES;

    dora_weight_kernel<<<OUT_DIM, 256, 0, stream>>>(W, dre, dimg, mrow, Wd);

    dim3 grid(MROWS / BM, OUT_DIM / BN);
    if (fast) {
        cvt_kernel<<<(MROWS * (size_t)IN_DIM / 8) / 256, 256, 0, stream>>>(x, Xb);
        gemm_kernel<true><<<grid, dim3(256), 0, stream>>>(x, Xb, Wd, bias, out);
    } else {
        gemm_kernel<false><<<grid, dim3(256), 0, stream>>>(x, Wd, Wd, bias, out);
    }
}

// Round 2
// 345.811 us; speedup vs baseline: 1.3413x; 1.3413x over previous
//
#include <hip/hip_runtime.h>
#include <hip/hip_bf16.h>

typedef __attribute__((ext_vector_type(4))) float f32x4;
typedef __attribute__((ext_vector_type(8))) short bf16x8;

#define IN_DIM 4096
#define OUT_DIM 4096
#define MROWS 8192   // B*S = 4*2048
#define NFREQ 8
#define TWO_PI 6.283185307179586f

// 8-phase 256x256 GEMM geometry
#define BK 64
#define NT (IN_DIM / BK)        // 64 K-tiles
#define LDS_BUF 32768           // one operand buffer (256x64 bf16)
#define LDS_HALF 16384          // half buffer (128x64 bf16)
#define LDS_B_REGION 65536      // B region base byte

// f32 -> bf16 bits, round-to-nearest-even
__device__ __forceinline__ unsigned int f2bf(float f) {
    union { float f; unsigned int u; } a;
    a.f = f;
    unsigned int u = a.u;
    u += 0x7fffu + ((u >> 16) & 1u);
    return u >> 16;
}

// ---------------------------------------------------------------------------
// Kernel 1: W_dora (bf16) = m * (W + irfft2(pad(delta))) / (rownorm + eps)
// ---------------------------------------------------------------------------
__global__ __launch_bounds__(256) void dora_weight_kernel(
    const float* __restrict__ W,
    const float* __restrict__ dre,
    const float* __restrict__ dimg,
    const float* __restrict__ mrow,
    unsigned short* __restrict__ Wd)
{
    const int o = blockIdx.x;
    const int t = threadIdx.x;

    float P[NFREQ], Q[NFREQ];
#pragma unroll
    for (int w = 0; w < NFREQ; ++w) { P[w] = 0.f; Q[w] = 0.f; }
#pragma unroll
    for (int h = 0; h < NFREQ; ++h) {
        const float th = (TWO_PI / 4096.0f) * (float)((h * o) & 4095);
        float sh, ch;
        sincosf(th, &sh, &ch);
#pragma unroll
        for (int w = 0; w < NFREQ; ++w) {
            const float A = 2.0f * dre[h * NFREQ + w];
            const float B = 2.0f * dimg[h * NFREQ + w];
            P[w] += A * ch - B * sh;
            Q[w] += A * sh + B * ch;
        }
    }
#pragma unroll
    for (int w = 0; w < NFREQ; ++w) {
        const float c = (w == 0 ? 1.0f : 2.0f) * (1.0f / 4096.0f);
        P[w] *= c; Q[w] *= c;
    }

    const int i0 = t * 16;
    const f32x4* wrow = (const f32x4*)(W + (size_t)o * IN_DIM + i0);
    float vals[16];
    float ss = 0.0f;
#pragma unroll
    for (int q = 0; q < 4; ++q) {
        const f32x4 wv = wrow[q];
#pragma unroll
        for (int j = 0; j < 4; ++j) {
            const int i = i0 + q * 4 + j;
            const float beta = (TWO_PI / 4096.0f) * (float)i;
            float sb, cb;
            sincosf(beta, &sb, &cb);
            float cw = cb, sw = sb;
            float d = P[0] + P[1] * cw - Q[1] * sw;
#pragma unroll
            for (int w = 2; w < NFREQ; ++w) {
                const float cn = cw * cb - sw * sb;
                sw = sw * cb + cw * sb;
                cw = cn;
                d += P[w] * cw - Q[w] * sw;
            }
            const float v = wv[j] + d;
            vals[q * 4 + j] = v;
            ss += v * v;
        }
    }

#pragma unroll
    for (int off = 32; off > 0; off >>= 1)
        ss += __shfl_down(ss, off, 64);
    __shared__ float red[4];
    if ((t & 63) == 0) red[t >> 6] = ss;
    __syncthreads();
    const float n2 = red[0] + red[1] + red[2] + red[3];
    const float scale = mrow[o] / (sqrtf(n2) + 1e-8f);

    unsigned int wds[8];
#pragma unroll
    for (int k = 0; k < 8; ++k)
        wds[k] = f2bf(vals[2 * k] * scale) | (f2bf(vals[2 * k + 1] * scale) << 16);
    uint4* dst = (uint4*)(Wd + (size_t)o * IN_DIM + i0);
    dst[0] = make_uint4(wds[0], wds[1], wds[2], wds[3]);
    dst[1] = make_uint4(wds[4], wds[5], wds[6], wds[7]);
}

// ---------------------------------------------------------------------------
// Kernel 2: x (f32) -> bf16
// ---------------------------------------------------------------------------
__global__ __launch_bounds__(256) void cvt_kernel(
    const float* __restrict__ x, unsigned short* __restrict__ xb)
{
    const size_t idx = (size_t)blockIdx.x * 256 + threadIdx.x;
    const f32x4* p = (const f32x4*)(x + idx * 8);
    const f32x4 a = p[0], b = p[1];
    uint4 o;
    o.x = f2bf(a[0]) | (f2bf(a[1]) << 16);
    o.y = f2bf(a[2]) | (f2bf(a[3]) << 16);
    o.z = f2bf(b[0]) | (f2bf(b[1]) << 16);
    o.w = f2bf(b[2]) | (f2bf(b[3]) << 16);
    *(uint4*)(xb + idx * 8) = o;
}

// ---------------------------------------------------------------------------
// Kernel 3: 256x256-tile 8-phase bf16 GEMM (T2 swizzle + T3/T4 counted vmcnt
// + T5 setprio).  out[M,N] = Xb[M,K] @ Wd[N,K]^T + bias, f32 out.
//
// 8 waves (2M x 4N), per-wave output 128x64. LDS 128 KiB:
//   A: [2 buf][256 rows][64 cols] bf16 at byte 0
//   B: [2 buf][256 rows][64 cols] bf16 at byte 65536
// st_16x32 swizzle: byte ^= ((byte>>9)&1)<<5, applied as pre-swizzled global
// SOURCE (global_load_lds writes linearly) + swizzled ds_read address.
//
// Per K-tile t (buf b=t&1), 4 phases:
//   P1: rd A(mh0) 8x + B(nh0) 4x | stage Bh0(t+1)->b^1 | bar | lgkm0 | MFMA(0,0) | bar
//   P2: rd A(mh1) 8x             | stage Bh1(t+1)->b^1 | bar | lgkm0 | MFMA(1,0) | bar
//   P3: rd B(nh1) 4x             | stage Ah0(t+2)->b   | bar | lgkm0 | MFMA(1,1) | bar
//   P4: (no rd)                  | stage Ah1(t+2)->b   | bar | lgkm0 | MFMA(0,1)
//       | vmcnt(4) | bar
// Safety: A of tile t fully read by end of P2 (barrier-sealed) before P3/P4
// overwrite buf b's A halves; B of tile t-1 fully read by its P3 before this
// tile's P1/P2 write buf b^1's B halves. vmcnt(4) leaves only the two
// A(t+2) half-stages in flight across the tile boundary.
// ---------------------------------------------------------------------------

#define GLOAD(src, ldsoff)                                                    \
    __builtin_amdgcn_global_load_lds(                                         \
        (const __attribute__((address_space(1))) void*)(src),                 \
        (__attribute__((address_space(3))) void*)(smem + (ldsoff)), 16, 0, 0)

#define SBAR      asm volatile("s_barrier" ::: "memory")
#define WAITLGKM  asm volatile("s_waitcnt lgkmcnt(0)" ::: "memory")

__device__ __forceinline__ void mfma16(
    f32x4 (&acc)[8][4], const bf16x8 (&af)[4][2], const bf16x8 (&bf)[2][2],
    int MH, int NH)
{
#pragma unroll
    for (int ks = 0; ks < 2; ++ks)
#pragma unroll
        for (int mf = 0; mf < 4; ++mf)
#pragma unroll
            for (int nf = 0; nf < 2; ++nf)
                acc[MH * 4 + mf][NH * 2 + nf] =
                    __builtin_amdgcn_mfma_f32_16x16x32_bf16(
                        af[mf][ks], bf[nf][ks], acc[MH * 4 + mf][NH * 2 + nf],
                        0, 0, 0);
}

__global__ __launch_bounds__(512, 2) void gemm8_kernel(
    const unsigned short* __restrict__ Xb,
    const unsigned short* __restrict__ Wd,
    const float* __restrict__ bias,
    float* __restrict__ out)
{
    __shared__ __align__(1024) unsigned char smem[131072];

    const int tid = threadIdx.x;
    const int wid = tid >> 6, lane = tid & 63;
    const int wr = wid >> 2, wc = wid & 3;        // 2M x 4N waves
    const int fr = lane & 15, fq = lane >> 4;

    // XCD-aware block swizzle (512 blocks, 512%8==0 -> simple form bijective)
    const int bid = blockIdx.x;
    const int lin = (bid & 7) * 64 + (bid >> 3);
    const int tm = lin & 31, tn = lin >> 5;
    const int m0 = tm * 256, n0 = tn * 256;

    // ---- staging coords (pre-swizzled global source, linear LDS dest) ----
    const int srr = wid * 16 + (lane >> 3);                       // j=0 row in half
    const int scc = (((lane & 7) ^ (((lane >> 5) & 1) << 1))) * 8; // swz col
    const unsigned short* aS = Xb + (size_t)(m0 + srr) * IN_DIM + scc;
    const unsigned short* bS = Wd + (size_t)(n0 + srr) * IN_DIM + scc;
    const int sdst = wid * 2048;                                  // + j*1024

    // ---- ds_read lane bases (swizzled) ----
    const int cbyte = (fq * 16) ^ (((fr >> 2) & 1) << 5);
    const int aBase = (wr * 128 + fr) * 128 + cbyte;  // + b*32768 + mh*8192 + mf*2048 + ks*64
    const int bBase = LDS_B_REGION + (wc * 64 + fr) * 128 + cbyte; // + b*32768 + nh*4096 + nf*2048 + ks*64

    auto STAGE = [&](int buf, int isB, int half, int tt) {
        const unsigned short* s =
            (isB ? bS : aS) + (size_t)half * 128 * IN_DIM + (size_t)tt * BK;
        const int d = buf * LDS_BUF + isB * LDS_B_REGION + half * LDS_HALF + sdst;
        GLOAD(s, d);
        GLOAD(s + 8 * IN_DIM, d + 1024);
    };

    f32x4 acc[8][4] = {};
    bf16x8 a0[4][2], a1[4][2], bb[2][2];

    // ---- prologue: tile0 all 4 halves, tile1 A halves; drain tile0 ----
    STAGE(0, 0, 0, 0); STAGE(0, 0, 1, 0);
    STAGE(0, 1, 0, 0); STAGE(0, 1, 1, 0);
    STAGE(1, 0, 0, 1); STAGE(1, 0, 1, 1);
    asm volatile("s_waitcnt vmcnt(4)" ::: "memory");
    SBAR;

    for (int t = 0; t < NT; ++t) {
        const int b = t & 1;
        const int bo = b * LDS_BUF;
        const bool st1 = (t + 1 < NT);   // stage B(t+1)
        const bool st2 = (t + 2 < NT);   // stage A(t+2)

        // ---------------- P1: MFMA quad (0,0) ----------------
#pragma unroll
        for (int mf = 0; mf < 4; ++mf)
#pragma unroll
            for (int ks = 0; ks < 2; ++ks)
                a0[mf][ks] = *(const bf16x8*)(smem + bo + aBase + mf * 2048 + ks * 64);
#pragma unroll
        for (int nf = 0; nf < 2; ++nf)
#pragma unroll
            for (int ks = 0; ks < 2; ++ks)
                bb[nf][ks] = *(const bf16x8*)(smem + bo + bBase + nf * 2048 + ks * 64);
        if (st1) STAGE(b ^ 1, 1, 0, t + 1);
        SBAR;
        WAITLGKM;
        __builtin_amdgcn_s_setprio(1);
        mfma16(acc, a0, bb, 0, 0);
        __builtin_amdgcn_s_setprio(0);
        SBAR;

        // ---------------- P2: MFMA quad (1,0) ----------------
#pragma unroll
        for (int mf = 0; mf < 4; ++mf)
#pragma unroll
            for (int ks = 0; ks < 2; ++ks)
                a1[mf][ks] = *(const bf16x8*)(smem + bo + aBase + 8192 + mf * 2048 + ks * 64);
        if (st1) STAGE(b ^ 1, 1, 1, t + 1);
        SBAR;
        WAITLGKM;
        __builtin_amdgcn_s_setprio(1);
        mfma16(acc, a1, bb, 1, 0);
        __builtin_amdgcn_s_setprio(0);
        SBAR;

        // ---------------- P3: MFMA quad (1,1) ----------------
#pragma unroll
        for (int nf = 0; nf < 2; ++nf)
#pragma unroll
            for (int ks = 0; ks < 2; ++ks)
                bb[nf][ks] = *(const bf16x8*)(smem + bo + bBase + 4096 + nf * 2048 + ks * 64);
        if (st2) STAGE(b, 0, 0, t + 2);
        SBAR;
        WAITLGKM;
        __builtin_amdgcn_s_setprio(1);
        mfma16(acc, a1, bb, 1, 1);
        __builtin_amdgcn_s_setprio(0);
        SBAR;

        // ---------------- P4: MFMA quad (0,1) ----------------
        if (st2) STAGE(b, 0, 1, t + 2);
        SBAR;
        WAITLGKM;
        __builtin_amdgcn_s_setprio(1);
        mfma16(acc, a0, bb, 0, 1);
        __builtin_amdgcn_s_setprio(0);
        if (st2) {
            asm volatile("s_waitcnt vmcnt(4)" ::: "memory");
        } else {
            asm volatile("s_waitcnt vmcnt(0)" ::: "memory");
        }
        SBAR;
    }

    // ---- epilogue: bias add + f32 store ----
#pragma unroll
    for (int nf = 0; nf < 4; ++nf) {
        const int col = n0 + wc * 64 + nf * 16 + fr;
        const float bv = bias[col];
#pragma unroll
        for (int mf = 0; mf < 8; ++mf) {
            const int row = m0 + wr * 128 + mf * 16 + fq * 4;
            float* op = out + (size_t)row * OUT_DIM + col;
            op[0 * OUT_DIM] = acc[mf][nf][0] + bv;
            op[1 * OUT_DIM] = acc[mf][nf][1] + bv;
            op[2 * OUT_DIM] = acc[mf][nf][2] + bv;
            op[3 * OUT_DIM] = acc[mf][nf][3] + bv;
        }
    }
}

// ---------------------------------------------------------------------------
// Fallback GEMM (128x128, reg-staged f32 A) — only if ws too small for Xb.
// ---------------------------------------------------------------------------
__global__ __launch_bounds__(256) void gemm_fallback(
    const float* __restrict__ Xf,
    const unsigned short* __restrict__ Wd,
    const float* __restrict__ bias,
    float* __restrict__ out)
{
    __shared__ unsigned short As[2][128 * 32];
    __shared__ unsigned short Bs[2][128 * 32];

    const int t = threadIdx.x;
    const int wid = t >> 6, lane = t & 63;
    const int wr = wid >> 1, wc = wid & 1;
    const int m0 = blockIdx.x * 128, n0 = blockIdx.y * 128;
    const int fr = lane & 15, fq = lane >> 4;

    f32x4 acc[4][4] = {};

    const int srow = wid * 16 + (lane >> 2);
    const int scol = (lane & 3) * 8;
    const unsigned short* bsrc0 = Wd + (size_t)(n0 + srow) * IN_DIM + scol;
    const unsigned short* bsrc1 = bsrc0 + (size_t)64 * IN_DIM;
    const int lds_off = wid * 512;

    const int ar = t >> 1;
    const int ak = (t & 1) * 16;
    const float* afp = Xf + (size_t)(m0 + ar) * IN_DIM + ak;
    const int a_lds_off = ar * 32 + ak;

    auto stageB = [&](unsigned short* ldsbase, int kt) {
        __builtin_amdgcn_global_load_lds(
            (const __attribute__((address_space(1))) void*)(bsrc0 + kt * 32),
            (__attribute__((address_space(3))) void*)(ldsbase + lds_off), 16, 0, 0);
        __builtin_amdgcn_global_load_lds(
            (const __attribute__((address_space(1))) void*)(bsrc1 + kt * 32),
            (__attribute__((address_space(3))) void*)(ldsbase + 2048 + lds_off), 16, 0, 0);
    };
    auto writeA = [&](int buf, const f32x4* v) {
        unsigned int w[8];
#pragma unroll
        for (int k = 0; k < 4; ++k) {
            w[2 * k]     = f2bf(v[k][0]) | (f2bf(v[k][1]) << 16);
            w[2 * k + 1] = f2bf(v[k][2]) | (f2bf(v[k][3]) << 16);
        }
        uint4* d = (uint4*)(&As[buf][a_lds_off]);
        d[0] = make_uint4(w[0], w[1], w[2], w[3]);
        d[1] = make_uint4(w[4], w[5], w[6], w[7]);
    };

    stageB(Bs[0], 0);
    {
        f32x4 av[4];
        const f32x4* ap = (const f32x4*)afp;
        av[0] = ap[0]; av[1] = ap[1]; av[2] = ap[2]; av[3] = ap[3];
        writeA(0, av);
    }
    __syncthreads();

    for (int kt = 0; kt < IN_DIM / 32; ++kt) {
        const int cur = kt & 1;
        const bool more = (kt + 1 < IN_DIM / 32);
        f32x4 nv[4];
        if (more) {
            const f32x4* ap = (const f32x4*)(afp + (size_t)(kt + 1) * 32);
            nv[0] = ap[0]; nv[1] = ap[1]; nv[2] = ap[2]; nv[3] = ap[3];
            stageB(Bs[cur ^ 1], kt + 1);
        }
        bf16x8 afrag[4], bfrag[4];
#pragma unroll
        for (int mf = 0; mf < 4; ++mf)
            afrag[mf] = *(const bf16x8*)(&As[cur][(wr * 64 + mf * 16 + fr) * 32 + fq * 8]);
#pragma unroll
        for (int nf = 0; nf < 4; ++nf)
            bfrag[nf] = *(const bf16x8*)(&Bs[cur][(wc * 64 + nf * 16 + fr) * 32 + fq * 8]);
#pragma unroll
        for (int mf = 0; mf < 4; ++mf)
#pragma unroll
            for (int nf = 0; nf < 4; ++nf)
                acc[mf][nf] = __builtin_amdgcn_mfma_f32_16x16x32_bf16(
                    afrag[mf], bfrag[nf], acc[mf][nf], 0, 0, 0);
        if (more) writeA(cur ^ 1, nv);
        __syncthreads();
    }

#pragma unroll
    for (int nf = 0; nf < 4; ++nf) {
        const int col = n0 + wc * 64 + nf * 16 + fr;
        const float bv = bias[col];
#pragma unroll
        for (int mf = 0; mf < 4; ++mf) {
            const int row = m0 + wr * 64 + mf * 16 + fq * 4;
            float* op = out + (size_t)row * OUT_DIM + col;
            op[0 * OUT_DIM] = acc[mf][nf][0] + bv;
            op[1 * OUT_DIM] = acc[mf][nf][1] + bv;
            op[2 * OUT_DIM] = acc[mf][nf][2] + bv;
            op[3 * OUT_DIM] = acc[mf][nf][3] + bv;
        }
    }
}

extern "C" void kernel_launch(void* const* d_in, const int* in_sizes, int n_in,
                              void* d_out, int out_size, void* d_ws, size_t ws_size,
                              hipStream_t stream) {
    const float* x    = (const float*)d_in[0];
    const float* W    = (const float*)d_in[1];
    const float* bias = (const float*)d_in[2];
    const float* dre  = (const float*)d_in[3];
    const float* dimg = (const float*)d_in[4];
    const float* mrow = (const float*)d_in[5];
    float* out = (float*)d_out;

    unsigned short* Wd = (unsigned short*)d_ws;
    const size_t WD_BYTES = (size_t)OUT_DIM * IN_DIM * 2;   // 32 MiB
    const size_t XB_BYTES = (size_t)MROWS * IN_DIM * 2;     // 64 MiB
    unsigned short* Xb = (unsigned short*)((char*)d_ws + WD_BYTES);
    const bool fast = ws_size >= WD_BYTES + XB_BYTES;

    dora_weight_kernel<<<OUT_DIM, 256, 0, stream>>>(W, dre, dimg, mrow, Wd);

    if (fast) {
        cvt_kernel<<<(MROWS * (size_t)IN_DIM / 8) / 256, 256, 0, stream>>>(x, Xb);
        gemm8_kernel<<<dim3((MROWS / 256) * (OUT_DIM / 256)), dim3(512), 0, stream>>>(
            Xb, Wd, bias, out);
    } else {
        dim3 grid(MROWS / 128, OUT_DIM / 128);
        gemm_fallback<<<grid, dim3(256), 0, stream>>>(x, Wd, bias, out);
    }
}

// Round 3
// 331.650 us; speedup vs baseline: 1.3986x; 1.0427x over previous
//
#include <hip/hip_runtime.h>
#include <hip/hip_bf16.h>

typedef __attribute__((ext_vector_type(4))) float f32x4;
typedef __attribute__((ext_vector_type(8))) short bf16x8;

#define IN_DIM 4096
#define OUT_DIM 4096
#define MROWS 8192   // B*S = 4*2048
#define NFREQ 8
#define TWO_PI 6.283185307179586f

// 8-phase 256x256 GEMM geometry
#define BK 64
#define NT (IN_DIM / BK)        // 64 K-tiles
#define LDS_BUF 32768           // one operand buffer (256x64 bf16)
#define LDS_HALF 16384          // half buffer (128x64 bf16)
#define LDS_B_REGION 65536      // B region base byte

// f32 -> bf16 bits, round-to-nearest-even
__device__ __forceinline__ unsigned int f2bf(float f) {
    union { float f; unsigned int u; } a;
    a.f = f;
    unsigned int u = a.u;
    u += 0x7fffu + ((u >> 16) & 1u);
    return u >> 16;
}

// ---------------------------------------------------------------------------
// Kernel 1: W_dora (bf16) = m * (W + irfft2(pad(delta))) / (rownorm + eps)
// ---------------------------------------------------------------------------
__global__ __launch_bounds__(256) void dora_weight_kernel(
    const float* __restrict__ W,
    const float* __restrict__ dre,
    const float* __restrict__ dimg,
    const float* __restrict__ mrow,
    unsigned short* __restrict__ Wd)
{
    const int o = blockIdx.x;
    const int t = threadIdx.x;

    float P[NFREQ], Q[NFREQ];
#pragma unroll
    for (int w = 0; w < NFREQ; ++w) { P[w] = 0.f; Q[w] = 0.f; }
#pragma unroll
    for (int h = 0; h < NFREQ; ++h) {
        const float th = (TWO_PI / 4096.0f) * (float)((h * o) & 4095);
        float sh, ch;
        sincosf(th, &sh, &ch);
#pragma unroll
        for (int w = 0; w < NFREQ; ++w) {
            const float A = 2.0f * dre[h * NFREQ + w];
            const float B = 2.0f * dimg[h * NFREQ + w];
            P[w] += A * ch - B * sh;
            Q[w] += A * sh + B * ch;
        }
    }
#pragma unroll
    for (int w = 0; w < NFREQ; ++w) {
        const float c = (w == 0 ? 1.0f : 2.0f) * (1.0f / 4096.0f);
        P[w] *= c; Q[w] *= c;
    }

    const int i0 = t * 16;
    const f32x4* wrow = (const f32x4*)(W + (size_t)o * IN_DIM + i0);
    float vals[16];
    float ss = 0.0f;
#pragma unroll
    for (int q = 0; q < 4; ++q) {
        const f32x4 wv = wrow[q];
#pragma unroll
        for (int j = 0; j < 4; ++j) {
            const int i = i0 + q * 4 + j;
            const float beta = (TWO_PI / 4096.0f) * (float)i;
            float sb, cb;
            sincosf(beta, &sb, &cb);
            float cw = cb, sw = sb;
            float d = P[0] + P[1] * cw - Q[1] * sw;
#pragma unroll
            for (int w = 2; w < NFREQ; ++w) {
                const float cn = cw * cb - sw * sb;
                sw = sw * cb + cw * sb;
                cw = cn;
                d += P[w] * cw - Q[w] * sw;
            }
            const float v = wv[j] + d;
            vals[q * 4 + j] = v;
            ss += v * v;
        }
    }

#pragma unroll
    for (int off = 32; off > 0; off >>= 1)
        ss += __shfl_down(ss, off, 64);
    __shared__ float red[4];
    if ((t & 63) == 0) red[t >> 6] = ss;
    __syncthreads();
    const float n2 = red[0] + red[1] + red[2] + red[3];
    const float scale = mrow[o] / (sqrtf(n2) + 1e-8f);

    unsigned int wds[8];
#pragma unroll
    for (int k = 0; k < 8; ++k)
        wds[k] = f2bf(vals[2 * k] * scale) | (f2bf(vals[2 * k + 1] * scale) << 16);
    uint4* dst = (uint4*)(Wd + (size_t)o * IN_DIM + i0);
    dst[0] = make_uint4(wds[0], wds[1], wds[2], wds[3]);
    dst[1] = make_uint4(wds[4], wds[5], wds[6], wds[7]);
}

// ---------------------------------------------------------------------------
// Kernel 2: x (f32) -> bf16
// ---------------------------------------------------------------------------
__global__ __launch_bounds__(256) void cvt_kernel(
    const float* __restrict__ x, unsigned short* __restrict__ xb)
{
    const size_t idx = (size_t)blockIdx.x * 256 + threadIdx.x;
    const f32x4* p = (const f32x4*)(x + idx * 8);
    const f32x4 a = p[0], b = p[1];
    uint4 o;
    o.x = f2bf(a[0]) | (f2bf(a[1]) << 16);
    o.y = f2bf(a[2]) | (f2bf(a[3]) << 16);
    o.z = f2bf(b[0]) | (f2bf(b[1]) << 16);
    o.w = f2bf(b[2]) | (f2bf(b[3]) << 16);
    *(uint4*)(xb + idx * 8) = o;
}

// ---------------------------------------------------------------------------
// Kernel 3: 256x256-tile 8-phase bf16 GEMM.
//
// LDS swizzle (3-bit, full bank spread): LDS slot (row rr, 16B-chunk c)
// holds global chunk  c ^ (rr & 7).
//   - staging: global_load_lds writes linearly (lane l -> byte l*16), so the
//     SOURCE column is pre-swizzled: lane l reads global chunk (l&7)^(l>>3)
//     (rr&7 == l>>3 for both j sub-rows).
//   - read: to get global chunk g at row rr, read chunk g^(rr&7):
//     byte = rr*128 + ((ks*4+fq)^(fr&7))*16  ->  base ^ (ks<<6).
// Per quarter-wave (16 lanes, fixed fq): 8 distinct chunks x 2 lanes = 2-way
// (free). Previous 1-bit swizzle left an 8-way conflict (2.5e7 counts).
//
// Phases per K-tile t (buf b=t&1):
//   P1: rd A(mh0)+B(nh0) | stage Bh0(t+1)->b^1 | bar|lgkm0|MFMA(0,0)|bar
//   P2: rd A(mh1)        | stage Bh1(t+1)->b^1 | bar|lgkm0|MFMA(1,0)|bar
//   P3: rd B(nh1)        | stage Ah0(t+2)->b   | bar|lgkm0|MFMA(1,1)|bar
//   P4:                  | stage Ah1(t+2)->b   | bar|lgkm0|MFMA(0,1)
//       | vmcnt(4) | bar
// ---------------------------------------------------------------------------

#define GLOAD(src, ldsoff)                                                    \
    __builtin_amdgcn_global_load_lds(                                         \
        (const __attribute__((address_space(1))) void*)(src),                 \
        (__attribute__((address_space(3))) void*)(smem + (ldsoff)), 16, 0, 0)

#define SBAR      asm volatile("s_barrier" ::: "memory")
#define WAITLGKM  asm volatile("s_waitcnt lgkmcnt(0)" ::: "memory")

__device__ __forceinline__ void mfma16(
    f32x4 (&acc)[8][4], const bf16x8 (&af)[4][2], const bf16x8 (&bf)[2][2],
    int MH, int NH)
{
#pragma unroll
    for (int ks = 0; ks < 2; ++ks)
#pragma unroll
        for (int mf = 0; mf < 4; ++mf)
#pragma unroll
            for (int nf = 0; nf < 2; ++nf)
                acc[MH * 4 + mf][NH * 2 + nf] =
                    __builtin_amdgcn_mfma_f32_16x16x32_bf16(
                        af[mf][ks], bf[nf][ks], acc[MH * 4 + mf][NH * 2 + nf],
                        0, 0, 0);
}

__global__ __launch_bounds__(512, 2) void gemm8_kernel(
    const unsigned short* __restrict__ Xb,
    const unsigned short* __restrict__ Wd,
    const float* __restrict__ bias,
    float* __restrict__ out)
{
    __shared__ __align__(1024) unsigned char smem[131072];

    const int tid = threadIdx.x;
    const int wid = tid >> 6, lane = tid & 63;
    const int wr = wid >> 2, wc = wid & 3;        // 2M x 4N waves
    const int fr = lane & 15, fq = lane >> 4;

    // XCD-aware block swizzle (512 blocks, 512%8==0 -> bijective)
    const int bid = blockIdx.x;
    const int lin = (bid & 7) * 64 + (bid >> 3);
    const int tm = lin & 31, tn = lin >> 5;
    const int m0 = tm * 256, n0 = tn * 256;

    // ---- staging coords: pre-swizzled global source, linear LDS dest ----
    const int srr = wid * 16 + (lane >> 3);                 // j=0 row in half
    const int scc = ((lane & 7) ^ (lane >> 3)) * 8;         // swizzled col (elems)
    const unsigned short* aS = Xb + (size_t)(m0 + srr) * IN_DIM + scc;
    const unsigned short* bS = Wd + (size_t)(n0 + srr) * IN_DIM + scc;
    const int sdst = wid * 2048;                            // + j*1024

    // ---- ds_read lane bases (swizzled, per-ks via XOR 64) ----
    const int cbyte = ((fq ^ (fr & 7)) * 16);               // ks=0 chunk byte
    const int aBase0 = (wr * 128 + fr) * 128 + cbyte;       // + b*32768 + mh*8192 + mf*2048
    const int aBase1 = aBase0 ^ 64;                         // ks=1
    const int bBase0 = LDS_B_REGION + (wc * 64 + fr) * 128 + cbyte; // + b*32768 + nh*4096 + nf*2048
    const int bBase1 = bBase0 ^ 64;

    auto STAGE = [&](int buf, int isB, int half, int tt) {
        const unsigned short* s =
            (isB ? bS : aS) + (size_t)half * 128 * IN_DIM + (size_t)tt * BK;
        const int d = buf * LDS_BUF + isB * LDS_B_REGION + half * LDS_HALF + sdst;
        GLOAD(s, d);
        GLOAD(s + 8 * IN_DIM, d + 1024);
    };

    f32x4 acc[8][4] = {};
    bf16x8 a0[4][2], a1[4][2], bb[2][2];

    // ---- prologue: tile0 all 4 halves, tile1 A halves; drain tile0 ----
    STAGE(0, 0, 0, 0); STAGE(0, 0, 1, 0);
    STAGE(0, 1, 0, 0); STAGE(0, 1, 1, 0);
    STAGE(1, 0, 0, 1); STAGE(1, 0, 1, 1);
    asm volatile("s_waitcnt vmcnt(4)" ::: "memory");
    SBAR;

    for (int t = 0; t < NT; ++t) {
        const int b = t & 1;
        const int bo = b * LDS_BUF;
        const bool st1 = (t + 1 < NT);   // stage B(t+1)
        const bool st2 = (t + 2 < NT);   // stage A(t+2)

        // ---------------- P1: MFMA quad (0,0) ----------------
#pragma unroll
        for (int mf = 0; mf < 4; ++mf) {
            a0[mf][0] = *(const bf16x8*)(smem + bo + aBase0 + mf * 2048);
            a0[mf][1] = *(const bf16x8*)(smem + bo + aBase1 + mf * 2048);
        }
#pragma unroll
        for (int nf = 0; nf < 2; ++nf) {
            bb[nf][0] = *(const bf16x8*)(smem + bo + bBase0 + nf * 2048);
            bb[nf][1] = *(const bf16x8*)(smem + bo + bBase1 + nf * 2048);
        }
        if (st1) STAGE(b ^ 1, 1, 0, t + 1);
        SBAR;
        WAITLGKM;
        __builtin_amdgcn_s_setprio(1);
        mfma16(acc, a0, bb, 0, 0);
        __builtin_amdgcn_s_setprio(0);
        SBAR;

        // ---------------- P2: MFMA quad (1,0) ----------------
#pragma unroll
        for (int mf = 0; mf < 4; ++mf) {
            a1[mf][0] = *(const bf16x8*)(smem + bo + aBase0 + 8192 + mf * 2048);
            a1[mf][1] = *(const bf16x8*)(smem + bo + aBase1 + 8192 + mf * 2048);
        }
        if (st1) STAGE(b ^ 1, 1, 1, t + 1);
        SBAR;
        WAITLGKM;
        __builtin_amdgcn_s_setprio(1);
        mfma16(acc, a1, bb, 1, 0);
        __builtin_amdgcn_s_setprio(0);
        SBAR;

        // ---------------- P3: MFMA quad (1,1) ----------------
#pragma unroll
        for (int nf = 0; nf < 2; ++nf) {
            bb[nf][0] = *(const bf16x8*)(smem + bo + bBase0 + 4096 + nf * 2048);
            bb[nf][1] = *(const bf16x8*)(smem + bo + bBase1 + 4096 + nf * 2048);
        }
        if (st2) STAGE(b, 0, 0, t + 2);
        SBAR;
        WAITLGKM;
        __builtin_amdgcn_s_setprio(1);
        mfma16(acc, a1, bb, 1, 1);
        __builtin_amdgcn_s_setprio(0);
        SBAR;

        // ---------------- P4: MFMA quad (0,1) ----------------
        if (st2) STAGE(b, 0, 1, t + 2);
        SBAR;
        WAITLGKM;
        __builtin_amdgcn_s_setprio(1);
        mfma16(acc, a0, bb, 0, 1);
        __builtin_amdgcn_s_setprio(0);
        if (st2) {
            asm volatile("s_waitcnt vmcnt(4)" ::: "memory");
        } else {
            asm volatile("s_waitcnt vmcnt(0)" ::: "memory");
        }
        SBAR;
    }

    // ---- epilogue: bias add + f32 store ----
#pragma unroll
    for (int nf = 0; nf < 4; ++nf) {
        const int col = n0 + wc * 64 + nf * 16 + fr;
        const float bv = bias[col];
#pragma unroll
        for (int mf = 0; mf < 8; ++mf) {
            const int row = m0 + wr * 128 + mf * 16 + fq * 4;
            float* op = out + (size_t)row * OUT_DIM + col;
            op[0 * OUT_DIM] = acc[mf][nf][0] + bv;
            op[1 * OUT_DIM] = acc[mf][nf][1] + bv;
            op[2 * OUT_DIM] = acc[mf][nf][2] + bv;
            op[3 * OUT_DIM] = acc[mf][nf][3] + bv;
        }
    }
}

// ---------------------------------------------------------------------------
// Fallback GEMM (128x128, reg-staged f32 A) — only if ws too small for Xb.
// ---------------------------------------------------------------------------
__global__ __launch_bounds__(256) void gemm_fallback(
    const float* __restrict__ Xf,
    const unsigned short* __restrict__ Wd,
    const float* __restrict__ bias,
    float* __restrict__ out)
{
    __shared__ unsigned short As[2][128 * 32];
    __shared__ unsigned short Bs[2][128 * 32];

    const int t = threadIdx.x;
    const int wid = t >> 6, lane = t & 63;
    const int wr = wid >> 1, wc = wid & 1;
    const int m0 = blockIdx.x * 128, n0 = blockIdx.y * 128;
    const int fr = lane & 15, fq = lane >> 4;

    f32x4 acc[4][4] = {};

    const int srow = wid * 16 + (lane >> 2);
    const int scol = (lane & 3) * 8;
    const unsigned short* bsrc0 = Wd + (size_t)(n0 + srow) * IN_DIM + scol;
    const unsigned short* bsrc1 = bsrc0 + (size_t)64 * IN_DIM;
    const int lds_off = wid * 512;

    const int ar = t >> 1;
    const int ak = (t & 1) * 16;
    const float* afp = Xf + (size_t)(m0 + ar) * IN_DIM + ak;
    const int a_lds_off = ar * 32 + ak;

    auto stageB = [&](unsigned short* ldsbase, int kt) {
        __builtin_amdgcn_global_load_lds(
            (const __attribute__((address_space(1))) void*)(bsrc0 + kt * 32),
            (__attribute__((address_space(3))) void*)(ldsbase + lds_off), 16, 0, 0);
        __builtin_amdgcn_global_load_lds(
            (const __attribute__((address_space(1))) void*)(bsrc1 + kt * 32),
            (__attribute__((address_space(3))) void*)(ldsbase + 2048 + lds_off), 16, 0, 0);
    };
    auto writeA = [&](int buf, const f32x4* v) {
        unsigned int w[8];
#pragma unroll
        for (int k = 0; k < 4; ++k) {
            w[2 * k]     = f2bf(v[k][0]) | (f2bf(v[k][1]) << 16);
            w[2 * k + 1] = f2bf(v[k][2]) | (f2bf(v[k][3]) << 16);
        }
        uint4* d = (uint4*)(&As[buf][a_lds_off]);
        d[0] = make_uint4(w[0], w[1], w[2], w[3]);
        d[1] = make_uint4(w[4], w[5], w[6], w[7]);
    };

    stageB(Bs[0], 0);
    {
        f32x4 av[4];
        const f32x4* ap = (const f32x4*)afp;
        av[0] = ap[0]; av[1] = ap[1]; av[2] = ap[2]; av[3] = ap[3];
        writeA(0, av);
    }
    __syncthreads();

    for (int kt = 0; kt < IN_DIM / 32; ++kt) {
        const int cur = kt & 1;
        const bool more = (kt + 1 < IN_DIM / 32);
        f32x4 nv[4];
        if (more) {
            const f32x4* ap = (const f32x4*)(afp + (size_t)(kt + 1) * 32);
            nv[0] = ap[0]; nv[1] = ap[1]; nv[2] = ap[2]; nv[3] = ap[3];
            stageB(Bs[cur ^ 1], kt + 1);
        }
        bf16x8 afrag[4], bfrag[4];
#pragma unroll
        for (int mf = 0; mf < 4; ++mf)
            afrag[mf] = *(const bf16x8*)(&As[cur][(wr * 64 + mf * 16 + fr) * 32 + fq * 8]);
#pragma unroll
        for (int nf = 0; nf < 4; ++nf)
            bfrag[nf] = *(const bf16x8*)(&Bs[cur][(wc * 64 + nf * 16 + fr) * 32 + fq * 8]);
#pragma unroll
        for (int mf = 0; mf < 4; ++mf)
#pragma unroll
            for (int nf = 0; nf < 4; ++nf)
                acc[mf][nf] = __builtin_amdgcn_mfma_f32_16x16x32_bf16(
                    afrag[mf], bfrag[nf], acc[mf][nf], 0, 0, 0);
        if (more) writeA(cur ^ 1, nv);
        __syncthreads();
    }

#pragma unroll
    for (int nf = 0; nf < 4; ++nf) {
        const int col = n0 + wc * 64 + nf * 16 + fr;
        const float bv = bias[col];
#pragma unroll
        for (int mf = 0; mf < 4; ++mf) {
            const int row = m0 + wr * 64 + mf * 16 + fq * 4;
            float* op = out + (size_t)row * OUT_DIM + col;
            op[0 * OUT_DIM] = acc[mf][nf][0] + bv;
            op[1 * OUT_DIM] = acc[mf][nf][1] + bv;
            op[2 * OUT_DIM] = acc[mf][nf][2] + bv;
            op[3 * OUT_DIM] = acc[mf][nf][3] + bv;
        }
    }
}

extern "C" void kernel_launch(void* const* d_in, const int* in_sizes, int n_in,
                              void* d_out, int out_size, void* d_ws, size_t ws_size,
                              hipStream_t stream) {
    const float* x    = (const float*)d_in[0];
    const float* W    = (const float*)d_in[1];
    const float* bias = (const float*)d_in[2];
    const float* dre  = (const float*)d_in[3];
    const float* dimg = (const float*)d_in[4];
    const float* mrow = (const float*)d_in[5];
    float* out = (float*)d_out;

    unsigned short* Wd = (unsigned short*)d_ws;
    const size_t WD_BYTES = (size_t)OUT_DIM * IN_DIM * 2;   // 32 MiB
    const size_t XB_BYTES = (size_t)MROWS * IN_DIM * 2;     // 64 MiB
    unsigned short* Xb = (unsigned short*)((char*)d_ws + WD_BYTES);
    const bool fast = ws_size >= WD_BYTES + XB_BYTES;

    dora_weight_kernel<<<OUT_DIM, 256, 0, stream>>>(W, dre, dimg, mrow, Wd);

    if (fast) {
        cvt_kernel<<<(MROWS * (size_t)IN_DIM / 8) / 256, 256, 0, stream>>>(x, Xb);
        gemm8_kernel<<<dim3((MROWS / 256) * (OUT_DIM / 256)), dim3(512), 0, stream>>>(
            Xb, Wd, bias, out);
    } else {
        dim3 grid(MROWS / 128, OUT_DIM / 128);
        gemm_fallback<<<grid, dim3(256), 0, stream>>>(x, Wd, bias, out);
    }
}

// Round 4
// 310.272 us; speedup vs baseline: 1.4949x; 1.0689x over previous
//
#include <hip/hip_runtime.h>
#include <hip/hip_bf16.h>

typedef __attribute__((ext_vector_type(4))) float f32x4;
typedef __attribute__((ext_vector_type(8))) short bf16x8;

#define IN_DIM 4096
#define OUT_DIM 4096
#define MROWS 8192   // B*S = 4*2048
#define NFREQ 8
#define TWO_PI 6.283185307179586f

// 8-phase 256x256 GEMM geometry
#define BK 64
#define NT (IN_DIM / BK)        // 64 K-tiles
#define LDS_BUF 32768           // one operand buffer (256x64 bf16)
#define LDS_HALF 16384          // half buffer (128x64 bf16)
#define LDS_B_REGION 65536      // B region base byte

// f32 -> bf16 bits, round-to-nearest-even
__device__ __forceinline__ unsigned int f2bf(float f) {
    union { float f; unsigned int u; } a;
    a.f = f;
    unsigned int u = a.u;
    u += 0x7fffu + ((u >> 16) & 1u);
    return u >> 16;
}

// ---------------------------------------------------------------------------
// Fused prep kernel.
//  blocks [0, 4096):      dora rows — W_dora(bf16) = m*(W+irfft2(pad(delta)))/(||row||+eps)
//  blocks [4096, 20480):  x f32 -> bf16 cvt
// HW trig (__sinf/__cosf -> v_sin/v_cos) + per-element rotation recurrence;
// error ~2^-20, negligible vs bf16 output rounding.
// ---------------------------------------------------------------------------
#define ROT_C 0.9999988234517019f
#define ROT_S 0.0015339801862847655f

__global__ __launch_bounds__(256) void prep_kernel(
    const float* __restrict__ x,
    const float* __restrict__ W,
    const float* __restrict__ dre,
    const float* __restrict__ dimg,
    const float* __restrict__ mrow,
    unsigned short* __restrict__ Wd,
    unsigned short* __restrict__ xb)
{
    const int t = threadIdx.x;

    if (blockIdx.x >= OUT_DIM) {
        // ---- cvt branch ----
        const size_t idx = (size_t)(blockIdx.x - OUT_DIM) * 256 + t;
        const f32x4* p = (const f32x4*)(x + idx * 8);
        const f32x4 a = p[0], b = p[1];
        uint4 o;
        o.x = f2bf(a[0]) | (f2bf(a[1]) << 16);
        o.y = f2bf(a[2]) | (f2bf(a[3]) << 16);
        o.z = f2bf(b[0]) | (f2bf(b[1]) << 16);
        o.w = f2bf(b[2]) | (f2bf(b[3]) << 16);
        *(uint4*)(xb + idx * 8) = o;
        return;
    }

    // ---- dora branch ----
    const int o = blockIdx.x;

    float P[NFREQ], Q[NFREQ];
#pragma unroll
    for (int w = 0; w < NFREQ; ++w) { P[w] = 0.f; Q[w] = 0.f; }
#pragma unroll
    for (int h = 0; h < NFREQ; ++h) {
        const float th = (TWO_PI / 4096.0f) * (float)((h * o) & 4095);
        const float sh = __sinf(th), ch = __cosf(th);
#pragma unroll
        for (int w = 0; w < NFREQ; ++w) {
            const float A = 2.0f * dre[h * NFREQ + w];
            const float B = 2.0f * dimg[h * NFREQ + w];
            P[w] += A * ch - B * sh;
            Q[w] += A * sh + B * ch;
        }
    }
#pragma unroll
    for (int w = 0; w < NFREQ; ++w) {
        const float c = (w == 0 ? 1.0f : 2.0f) * (1.0f / 4096.0f);
        P[w] *= c; Q[w] *= c;
    }

    const int i0 = t * 16;
    const f32x4* wrow = (const f32x4*)(W + (size_t)o * IN_DIM + i0);
    float vals[16];
    float ss = 0.0f;

    // base angle for element i0, then rotate by 2*pi/4096 per element
    const float beta0 = (TWO_PI / 4096.0f) * (float)i0;
    float cb = __cosf(beta0), sb = __sinf(beta0);

#pragma unroll
    for (int q = 0; q < 4; ++q) {
        const f32x4 wv = wrow[q];
#pragma unroll
        for (int j = 0; j < 4; ++j) {
            float cw = cb, sw = sb;
            float d = P[0] + P[1] * cw - Q[1] * sw;
#pragma unroll
            for (int w = 2; w < NFREQ; ++w) {
                const float cn = cw * cb - sw * sb;
                sw = sw * cb + cw * sb;
                cw = cn;
                d += P[w] * cw - Q[w] * sw;
            }
            const float v = wv[j] + d;
            vals[q * 4 + j] = v;
            ss += v * v;
            // rotate (cb,sb) to next element's angle
            const float cbn = cb * ROT_C - sb * ROT_S;
            sb = sb * ROT_C + cb * ROT_S;
            cb = cbn;
        }
    }

#pragma unroll
    for (int off = 32; off > 0; off >>= 1)
        ss += __shfl_down(ss, off, 64);
    __shared__ float red[4];
    if ((t & 63) == 0) red[t >> 6] = ss;
    __syncthreads();
    const float n2 = red[0] + red[1] + red[2] + red[3];
    const float scale = mrow[o] / (sqrtf(n2) + 1e-8f);

    unsigned int wds[8];
#pragma unroll
    for (int k = 0; k < 8; ++k)
        wds[k] = f2bf(vals[2 * k] * scale) | (f2bf(vals[2 * k + 1] * scale) << 16);
    uint4* dst = (uint4*)(Wd + (size_t)o * IN_DIM + i0);
    dst[0] = make_uint4(wds[0], wds[1], wds[2], wds[3]);
    dst[1] = make_uint4(wds[4], wds[5], wds[6], wds[7]);
}

// ---------------------------------------------------------------------------
// 256x256-tile bf16 GEMM, barrier-minimal deep-prefetch schedule.
//
// LDS swizzle (unchanged from R3, conflicts==0): slot (row rr, chunk c) holds
// global chunk c ^ (rr&7); staging pre-swizzles the global source column,
// reads XOR the chunk index.
//
// Schedule per K-tile t (buf b=t&1), 3 barriers/tile:
//   P1: rd a0(8) bb0(4) | STAGE Bh1(t+1)->b^1 | prio1 MFMA(0,0) prio0
//   P2: rd a1(8)        |                     | prio1 MFMA(1,0) prio0 | SBAR
//   P3: rd bb1(4)       | STAGE Ah0(t+2)->b   | prio1 MFMA(1,1) prio0 | SBAR
//   P4: STAGE Ah1(t+2)->b; STAGE Bh0(t+2)->b  | prio1 MFMA(0,1) prio0
//       | vmcnt(6) | SBAR
//
// Write-after-read ledger (who last reads each overwritten region, and the
// barrier that seals it):
//   Bh1(t+1)->b^1 @P1(t): b^1 B rows read through P3(t-1); sealed by P4(t-1)
//     tile-end SBAR (wave can't enter P1(t) before it).
//   Ah0(t+2)->b @P3(t): buf b A rows 0..127 last read: a0@P1 (wr=0 rows 0-63,
//     wr=1 128-191 -> h0 part rows 0-63) and a1@P2 (wr=0 rows 64-127). All
//     a-reads complete before each wave's P2 MFMA; sealed by P2-end SBAR.
//   Ah1(t+2)->b @P4(t): rows 128..255, last read a1@P2 (wr=1 rows 192-255) /
//     a0@P1 (128-191); sealed by P2-end + P3-end SBARs.
//   Bh0(t+2)->b @P4(t): buf b B rows 0..127 last read bb1@P3 (wc0/1 rows
//     32-63, 96-127); sealed by P3-end SBAR.
// Drain: vmcnt(6) at P4 waits exactly tile-(t+1)'s 4 half-stages (8 loads,
// ages 3-6 phases), leaving tile-(t+2)'s 3 half-stages (6 loads) in flight.
// Tail: vmcnt(0) when t+2>=NT.
// ---------------------------------------------------------------------------

#define GLOAD(src, ldsoff)                                                    \
    __builtin_amdgcn_global_load_lds(                                         \
        (const __attribute__((address_space(1))) void*)(src),                 \
        (__attribute__((address_space(3))) void*)(smem + (ldsoff)), 16, 0, 0)

#define SBAR asm volatile("s_barrier" ::: "memory")

__device__ __forceinline__ void mfma16(
    f32x4 (&acc)[8][4], const bf16x8 (&af)[4][2], const bf16x8 (&bf)[2][2],
    int MH, int NH)
{
#pragma unroll
    for (int ks = 0; ks < 2; ++ks)
#pragma unroll
        for (int mf = 0; mf < 4; ++mf)
#pragma unroll
            for (int nf = 0; nf < 2; ++nf)
                acc[MH * 4 + mf][NH * 2 + nf] =
                    __builtin_amdgcn_mfma_f32_16x16x32_bf16(
                        af[mf][ks], bf[nf][ks], acc[MH * 4 + mf][NH * 2 + nf],
                        0, 0, 0);
}

__global__ __launch_bounds__(512, 1) void gemm8_kernel(
    const unsigned short* __restrict__ Xb,
    const unsigned short* __restrict__ Wd,
    const float* __restrict__ bias,
    float* __restrict__ out)
{
    __shared__ __align__(1024) unsigned char smem[131072];

    const int tid = threadIdx.x;
    const int wid = tid >> 6, lane = tid & 63;
    const int wr = wid >> 2, wc = wid & 3;        // 2M x 4N waves
    const int fr = lane & 15, fq = lane >> 4;

    // XCD-aware block swizzle (512 blocks, 512%8==0 -> bijective)
    const int bid = blockIdx.x;
    const int lin = (bid & 7) * 64 + (bid >> 3);
    const int tm = lin & 31, tn = lin >> 5;
    const int m0 = tm * 256, n0 = tn * 256;

    // ---- staging coords: pre-swizzled global source, linear LDS dest ----
    const int srr = wid * 16 + (lane >> 3);                 // j=0 row in half
    const int scc = ((lane & 7) ^ (lane >> 3)) * 8;         // swizzled col (elems)
    const unsigned short* aS = Xb + (size_t)(m0 + srr) * IN_DIM + scc;
    const unsigned short* bS = Wd + (size_t)(n0 + srr) * IN_DIM + scc;
    const int sdst = wid * 2048;                            // + j*1024

    // ---- ds_read lane bases (swizzled, per-ks via XOR 64) ----
    const int cbyte = ((fq ^ (fr & 7)) * 16);               // ks=0 chunk byte
    const int aBase0 = (wr * 128 + fr) * 128 + cbyte;       // + b*32768 + mh*8192 + mf*2048
    const int aBase1 = aBase0 ^ 64;                         // ks=1
    const int bBase0 = LDS_B_REGION + (wc * 64 + fr) * 128 + cbyte; // + b*32768 + nh*4096 + nf*2048
    const int bBase1 = bBase0 ^ 64;

    auto STAGE = [&](int buf, int isB, int half, int tt) {
        const unsigned short* s =
            (isB ? bS : aS) + (size_t)half * 128 * IN_DIM + (size_t)tt * BK;
        const int d = buf * LDS_BUF + isB * LDS_B_REGION + half * LDS_HALF + sdst;
        GLOAD(s, d);
        GLOAD(s + 8 * IN_DIM, d + 1024);
    };

    f32x4 acc[8][4] = {};
    bf16x8 a0[4][2], a1[4][2], bb[2][2];

    // ---- prologue: tile0 (4 halves) + tile1 (Ah0, Ah1, Bh0); Bh1(1) comes
    // from P1 of tile 0. Drain tile0's 8 loads: vmcnt(6). ----
    STAGE(0, 0, 0, 0); STAGE(0, 0, 1, 0);
    STAGE(0, 1, 0, 0); STAGE(0, 1, 1, 0);
    STAGE(1, 0, 0, 1); STAGE(1, 0, 1, 1);
    STAGE(1, 1, 0, 1);
    asm volatile("s_waitcnt vmcnt(6)" ::: "memory");
    SBAR;

    for (int t = 0; t < NT; ++t) {
        const int b = t & 1;
        const int bo = b * LDS_BUF;
        const bool st1 = (t + 1 < NT);   // stage Bh1(t+1)
        const bool st2 = (t + 2 < NT);   // stage A(t+2), Bh0(t+2)

        // ---------------- P1: MFMA quad (0,0) ----------------
#pragma unroll
        for (int mf = 0; mf < 4; ++mf) {
            a0[mf][0] = *(const bf16x8*)(smem + bo + aBase0 + mf * 2048);
            a0[mf][1] = *(const bf16x8*)(smem + bo + aBase1 + mf * 2048);
        }
#pragma unroll
        for (int nf = 0; nf < 2; ++nf) {
            bb[nf][0] = *(const bf16x8*)(smem + bo + bBase0 + nf * 2048);
            bb[nf][1] = *(const bf16x8*)(smem + bo + bBase1 + nf * 2048);
        }
        if (st1) STAGE(b ^ 1, 1, 1, t + 1);
        __builtin_amdgcn_s_setprio(1);
        mfma16(acc, a0, bb, 0, 0);
        __builtin_amdgcn_s_setprio(0);

        // ---------------- P2: MFMA quad (1,0) ----------------
#pragma unroll
        for (int mf = 0; mf < 4; ++mf) {
            a1[mf][0] = *(const bf16x8*)(smem + bo + aBase0 + 8192 + mf * 2048);
            a1[mf][1] = *(const bf16x8*)(smem + bo + aBase1 + 8192 + mf * 2048);
        }
        __builtin_amdgcn_s_setprio(1);
        mfma16(acc, a1, bb, 1, 0);
        __builtin_amdgcn_s_setprio(0);
        SBAR;   // seals all A(t) reads -> A staging below may overwrite

        // ---------------- P3: MFMA quad (1,1) ----------------
#pragma unroll
        for (int nf = 0; nf < 2; ++nf) {
            bb[nf][0] = *(const bf16x8*)(smem + bo + bBase0 + 4096 + nf * 2048);
            bb[nf][1] = *(const bf16x8*)(smem + bo + bBase1 + 4096 + nf * 2048);
        }
        if (st2) STAGE(b, 0, 0, t + 2);
        __builtin_amdgcn_s_setprio(1);
        mfma16(acc, a1, bb, 1, 1);
        __builtin_amdgcn_s_setprio(0);
        SBAR;   // seals all B(t) reads -> B staging below may overwrite

        // ---------------- P4: MFMA quad (0,1) ----------------
        if (st2) { STAGE(b, 0, 1, t + 2); STAGE(b, 1, 0, t + 2); }
        __builtin_amdgcn_s_setprio(1);
        mfma16(acc, a0, bb, 0, 1);
        __builtin_amdgcn_s_setprio(0);
        if (st2) {
            asm volatile("s_waitcnt vmcnt(6)" ::: "memory");
        } else {
            asm volatile("s_waitcnt vmcnt(0)" ::: "memory");
        }
        SBAR;   // tile boundary
    }

    // ---- epilogue: bias add + f32 store ----
#pragma unroll
    for (int nf = 0; nf < 4; ++nf) {
        const int col = n0 + wc * 64 + nf * 16 + fr;
        const float bv = bias[col];
#pragma unroll
        for (int mf = 0; mf < 8; ++mf) {
            const int row = m0 + wr * 128 + mf * 16 + fq * 4;
            float* op = out + (size_t)row * OUT_DIM + col;
            op[0 * OUT_DIM] = acc[mf][nf][0] + bv;
            op[1 * OUT_DIM] = acc[mf][nf][1] + bv;
            op[2 * OUT_DIM] = acc[mf][nf][2] + bv;
            op[3 * OUT_DIM] = acc[mf][nf][3] + bv;
        }
    }
}

// ---------------------------------------------------------------------------
// Fallback GEMM (128x128, reg-staged f32 A) — only if ws too small for Xb.
// ---------------------------------------------------------------------------
__global__ __launch_bounds__(256) void gemm_fallback(
    const float* __restrict__ Xf,
    const unsigned short* __restrict__ Wd,
    const float* __restrict__ bias,
    float* __restrict__ out)
{
    __shared__ unsigned short As[2][128 * 32];
    __shared__ unsigned short Bs[2][128 * 32];

    const int t = threadIdx.x;
    const int wid = t >> 6, lane = t & 63;
    const int wr = wid >> 1, wc = wid & 1;
    const int m0 = blockIdx.x * 128, n0 = blockIdx.y * 128;
    const int fr = lane & 15, fq = lane >> 4;

    f32x4 acc[4][4] = {};

    const int srow = wid * 16 + (lane >> 2);
    const int scol = (lane & 3) * 8;
    const unsigned short* bsrc0 = Wd + (size_t)(n0 + srow) * IN_DIM + scol;
    const unsigned short* bsrc1 = bsrc0 + (size_t)64 * IN_DIM;
    const int lds_off = wid * 512;

    const int ar = t >> 1;
    const int ak = (t & 1) * 16;
    const float* afp = Xf + (size_t)(m0 + ar) * IN_DIM + ak;
    const int a_lds_off = ar * 32 + ak;

    auto stageB = [&](unsigned short* ldsbase, int kt) {
        __builtin_amdgcn_global_load_lds(
            (const __attribute__((address_space(1))) void*)(bsrc0 + kt * 32),
            (__attribute__((address_space(3))) void*)(ldsbase + lds_off), 16, 0, 0);
        __builtin_amdgcn_global_load_lds(
            (const __attribute__((address_space(1))) void*)(bsrc1 + kt * 32),
            (__attribute__((address_space(3))) void*)(ldsbase + 2048 + lds_off), 16, 0, 0);
    };
    auto writeA = [&](int buf, const f32x4* v) {
        unsigned int w[8];
#pragma unroll
        for (int k = 0; k < 4; ++k) {
            w[2 * k]     = f2bf(v[k][0]) | (f2bf(v[k][1]) << 16);
            w[2 * k + 1] = f2bf(v[k][2]) | (f2bf(v[k][3]) << 16);
        }
        uint4* d = (uint4*)(&As[buf][a_lds_off]);
        d[0] = make_uint4(w[0], w[1], w[2], w[3]);
        d[1] = make_uint4(w[4], w[5], w[6], w[7]);
    };

    stageB(Bs[0], 0);
    {
        f32x4 av[4];
        const f32x4* ap = (const f32x4*)afp;
        av[0] = ap[0]; av[1] = ap[1]; av[2] = ap[2]; av[3] = ap[3];
        writeA(0, av);
    }
    __syncthreads();

    for (int kt = 0; kt < IN_DIM / 32; ++kt) {
        const int cur = kt & 1;
        const bool more = (kt + 1 < IN_DIM / 32);
        f32x4 nv[4];
        if (more) {
            const f32x4* ap = (const f32x4*)(afp + (size_t)(kt + 1) * 32);
            nv[0] = ap[0]; nv[1] = ap[1]; nv[2] = ap[2]; nv[3] = ap[3];
            stageB(Bs[cur ^ 1], kt + 1);
        }
        bf16x8 afrag[4], bfrag[4];
#pragma unroll
        for (int mf = 0; mf < 4; ++mf)
            afrag[mf] = *(const bf16x8*)(&As[cur][(wr * 64 + mf * 16 + fr) * 32 + fq * 8]);
#pragma unroll
        for (int nf = 0; nf < 4; ++nf)
            bfrag[nf] = *(const bf16x8*)(&Bs[cur][(wc * 64 + nf * 16 + fr) * 32 + fq * 8]);
#pragma unroll
        for (int mf = 0; mf < 4; ++mf)
#pragma unroll
            for (int nf = 0; nf < 4; ++nf)
                acc[mf][nf] = __builtin_amdgcn_mfma_f32_16x16x32_bf16(
                    afrag[mf], bfrag[nf], acc[mf][nf], 0, 0, 0);
        if (more) writeA(cur ^ 1, nv);
        __syncthreads();
    }

#pragma unroll
    for (int nf = 0; nf < 4; ++nf) {
        const int col = n0 + wc * 64 + nf * 16 + fr;
        const float bv = bias[col];
#pragma unroll
        for (int mf = 0; mf < 4; ++mf) {
            const int row = m0 + wr * 64 + mf * 16 + fq * 4;
            float* op = out + (size_t)row * OUT_DIM + col;
            op[0 * OUT_DIM] = acc[mf][nf][0] + bv;
            op[1 * OUT_DIM] = acc[mf][nf][1] + bv;
            op[2 * OUT_DIM] = acc[mf][nf][2] + bv;
            op[3 * OUT_DIM] = acc[mf][nf][3] + bv;
        }
    }
}

extern "C" void kernel_launch(void* const* d_in, const int* in_sizes, int n_in,
                              void* d_out, int out_size, void* d_ws, size_t ws_size,
                              hipStream_t stream) {
    const float* x    = (const float*)d_in[0];
    const float* W    = (const float*)d_in[1];
    const float* bias = (const float*)d_in[2];
    const float* dre  = (const float*)d_in[3];
    const float* dimg = (const float*)d_in[4];
    const float* mrow = (const float*)d_in[5];
    float* out = (float*)d_out;

    unsigned short* Wd = (unsigned short*)d_ws;
    const size_t WD_BYTES = (size_t)OUT_DIM * IN_DIM * 2;   // 32 MiB
    const size_t XB_BYTES = (size_t)MROWS * IN_DIM * 2;     // 64 MiB
    unsigned short* Xb = (unsigned short*)((char*)d_ws + WD_BYTES);
    const bool fast = ws_size >= WD_BYTES + XB_BYTES;

    if (fast) {
        const int cvt_blocks = (MROWS * (size_t)IN_DIM / 8) / 256;  // 16384
        prep_kernel<<<OUT_DIM + cvt_blocks, 256, 0, stream>>>(
            x, W, dre, dimg, mrow, Wd, Xb);
        gemm8_kernel<<<dim3((MROWS / 256) * (OUT_DIM / 256)), dim3(512), 0, stream>>>(
            Xb, Wd, bias, out);
    } else {
        // slow path: dora (bf16 Wd) + fallback GEMM reading f32 x
        prep_kernel<<<OUT_DIM, 256, 0, stream>>>(x, W, dre, dimg, mrow, Wd, Wd);
        dim3 grid(MROWS / 128, OUT_DIM / 128);
        gemm_fallback<<<grid, dim3(256), 0, stream>>>(x, Wd, bias, out);
    }
}